// Round 1
// baseline (6560.889 us; speedup 1.0000x reference)
//
#include <hip/hip_runtime.h>
#include <stdint.h>

#define NB3 8112
#define NB4 2028
#define NB5 507
#define NTOT 10647           // 8112 + 2028 + 507
#define NBATCH 4
#define NCLS 20
#define NW 333               // ceil(10647 / 32)
#define LDS_CAP 9984         // boxes staged in LDS (16B each)
#define CONF_THR_F 0.1f
#define IOU_THR_F 0.45f

// ---------------------------------------------------------------------------
// Kernel A: per-box score / class argmax / sort key
// ---------------------------------------------------------------------------
__global__ void prep_kernel(const float* __restrict__ p3b, const float* __restrict__ p3c, const float* __restrict__ p3k,
                            const float* __restrict__ p4b, const float* __restrict__ p4c, const float* __restrict__ p4k,
                            const float* __restrict__ p5b, const float* __restrict__ p5c, const float* __restrict__ p5k,
                            uint64_t* __restrict__ keys, float4* __restrict__ boxes_cat,
                            float* __restrict__ score, int* __restrict__ clsidx, uint32_t* __restrict__ svout)
{
#pragma clang fp contract(off)
    int idx = blockIdx.x * 256 + threadIdx.x;
    if (idx >= NBATCH * NTOT) return;
    int b = idx / NTOT;
    int i = idx - b * NTOT;

    const float* bx; const float* cf; const float* cl; int n, off;
    if (i < NB3)            { bx = p3b; cf = p3c; cl = p3k; n = NB3; off = i; }
    else if (i < NB3 + NB4) { bx = p4b; cf = p4c; cl = p4k; n = NB4; off = i - NB3; }
    else                    { bx = p5b; cf = p5c; cl = p5k; n = NB5; off = i - NB3 - NB4; }

    size_t e = (size_t)b * n + off;
    float4 box = *(const float4*)(bx + e * 4);
    float conf = cf[e];
    const float* c = cl + e * NCLS;
    float m = c[0]; int mi = 0;
    #pragma unroll
    for (int k = 1; k < NCLS; ++k) { float v = c[k]; if (v > m) { m = v; mi = k; } }

    bool valid = conf > CONF_THR_F;
    float s = valid ? conf * m : 0.0f;           // exact: single f32 mul, no fma
    uint32_t sb = __float_as_uint(s);            // s >= 0 -> bits monotonic
    keys[idx]      = ((uint64_t)sb << 32) | (uint32_t)(0xFFFFFFFFu - (uint32_t)i);
    boxes_cat[idx] = box;
    score[idx]     = s;
    clsidx[idx]    = mi;
    svout[idx]     = valid ? 1u : 0u;
}

// ---------------------------------------------------------------------------
// Kernel B: stable descending rank sort (rank = #keys strictly greater),
// scatter sorted arrays, track nvalid = max(sorted pos of valid)+1
// ---------------------------------------------------------------------------
__global__ void rank_kernel(const uint64_t* __restrict__ keys,
                            const float4* __restrict__ boxes_cat,
                            const float* __restrict__ score,
                            const int* __restrict__ clsidx,
                            const uint32_t* __restrict__ sv,
                            float4* __restrict__ sboxes, float* __restrict__ sscore,
                            int* __restrict__ scls, uint32_t* __restrict__ ssv,
                            int* __restrict__ nvalid)
{
    int b = blockIdx.y;
    int i = blockIdx.x * 256 + threadIdx.x;
    const uint64_t* kb = keys + (size_t)b * NTOT;
    uint64_t mykey = (i < NTOT) ? kb[i] : 0ull;

    __shared__ uint64_t tile[256];
    int rank = 0;
    for (int t0 = 0; t0 < NTOT; t0 += 256) {
        int j = t0 + threadIdx.x;
        tile[threadIdx.x] = (j < NTOT) ? kb[j] : 0ull;   // 0 never > any real key
        __syncthreads();
        #pragma unroll 8
        for (int t = 0; t < 256; ++t) rank += (tile[t] > mykey) ? 1 : 0;
        __syncthreads();
    }

    if (i < NTOT) {
        size_t src = (size_t)b * NTOT + i;
        size_t dst = (size_t)b * NTOT + rank;
        sboxes[dst] = boxes_cat[src];
        sscore[dst] = score[src];
        scls[dst]   = clsidx[src];
        uint32_t v  = sv[src];
        ssv[dst]    = v;
        if (v) atomicMax(&nvalid[b], rank + 1);
    }
}

// ---------------------------------------------------------------------------
// Kernel C: greedy NMS, one block per image. Boxes staged in LDS (160KB opt-in),
// suppression + validity bitmasks in LDS.
// ---------------------------------------------------------------------------
extern __shared__ unsigned char nms_smem[];

__global__ void __launch_bounds__(1024) nms_kernel(const float4* __restrict__ sboxes,
                                                   const uint32_t* __restrict__ ssv,
                                                   const int* __restrict__ nvalid_arr,
                                                   uint32_t* __restrict__ supp_out)
{
#pragma clang fp contract(off)
    int b = blockIdx.x;
    float4*   lbox = (float4*)nms_smem;
    uint32_t* supp = (uint32_t*)(nms_smem + (size_t)LDS_CAP * 16);
    uint32_t* svb  = supp + NW;

    int nv = nvalid_arr[b];
    const float4* gb = sboxes + (size_t)b * NTOT;
    const uint32_t* gv = ssv + (size_t)b * NTOT;

    for (int t = threadIdx.x; t < NW; t += 1024) { supp[t] = 0u; svb[t] = 0u; }
    __syncthreads();
    for (int t = threadIdx.x; t < nv; t += 1024) {
        if (t < LDS_CAP) lbox[t] = gb[t];
        if (gv[t]) atomicOr(&svb[t >> 5], 1u << (t & 31));
    }
    __syncthreads();

    for (int i = 0; i < nv; ++i) {
        uint32_t sw = supp[i >> 5];            // uniform broadcast read
        if ((sw >> (i & 31)) & 1u) continue;   // already suppressed
        uint32_t vw = svb[i >> 5];
        if (!((vw >> (i & 31)) & 1u)) continue; // not valid -> cannot suppress

        float4 bi = (i < LDS_CAP) ? lbox[i] : gb[i];
        float ax1 = bi.x, ay1 = bi.y, ax2 = bi.z, ay2 = bi.w;
        float area_i = (ax2 - ax1) * (ay2 - ay1);

        for (int j = i + 1 + (int)threadIdx.x; j < nv; j += 1024) {
            float4 bj = (j < LDS_CAP) ? lbox[j] : gb[j];
            float xx1 = fmaxf(bj.x, ax1);
            float yy1 = fmaxf(bj.y, ay1);
            float xx2 = fminf(bj.z, ax2);
            float yy2 = fminf(bj.w, ay2);
            float w = fmaxf(xx2 - xx1, 0.0f);
            float h = fmaxf(yy2 - yy1, 0.0f);
            float inter  = w * h;
            float area_j = (bj.z - bj.x) * (bj.w - bj.y);
            float iou = inter / ((area_i + area_j) - inter);   // matches ref order
            if (iou > IOU_THR_F) atomicOr(&supp[j >> 5], 1u << (j & 31));
        }
        __syncthreads();
    }

    __syncthreads();
    for (int t = threadIdx.x; t < NW; t += 1024) supp_out[(size_t)b * NW + t] = supp[t];
}

// ---------------------------------------------------------------------------
// Kernel D: assemble outputs: dets [B,N,6] then keep [B,N] (as 0/1 floats)
// ---------------------------------------------------------------------------
__global__ void out_kernel(const float4* __restrict__ sboxes, const float* __restrict__ sscore,
                           const int* __restrict__ scls, const uint32_t* __restrict__ ssv,
                           const uint32_t* __restrict__ supp, float* __restrict__ out)
{
    int idx = blockIdx.x * 256 + threadIdx.x;
    if (idx >= NBATCH * NTOT) return;
    int b = idx / NTOT;
    int p = idx - b * NTOT;

    float4 box = sboxes[idx];
    uint32_t sup = (supp[(size_t)b * NW + (p >> 5)] >> (p & 31)) & 1u;
    bool keep = (ssv[idx] != 0u) && !sup;
    float sc = keep ? sscore[idx] : 0.0f;

    float* d = out + (size_t)idx * 6;
    d[0] = box.x; d[1] = box.y; d[2] = box.z; d[3] = box.w;
    d[4] = sc;    d[5] = (float)scls[idx];
    out[(size_t)NBATCH * NTOT * 6 + idx] = keep ? 1.0f : 0.0f;
}

// ---------------------------------------------------------------------------
extern "C" void kernel_launch(void* const* d_in, const int* in_sizes, int n_in,
                              void* d_out, int out_size, void* d_ws, size_t ws_size,
                              hipStream_t stream)
{
    const float* p3b = (const float*)d_in[0];
    const float* p3c = (const float*)d_in[1];
    const float* p3k = (const float*)d_in[2];
    const float* p4b = (const float*)d_in[3];
    const float* p4c = (const float*)d_in[4];
    const float* p4k = (const float*)d_in[5];
    const float* p5b = (const float*)d_in[6];
    const float* p5c = (const float*)d_in[7];
    const float* p5k = (const float*)d_in[8];
    float* out = (float*)d_out;

    // workspace carve-up (256B aligned slabs)
    char* ws = (char*)d_ws;
    size_t off = 0;
    auto alloc = [&](size_t bytes) { size_t o = off; off += (bytes + 255) & ~(size_t)255; return o; };
    const size_t BN = (size_t)NBATCH * NTOT;
    uint64_t* keys      = (uint64_t*)(ws + alloc(BN * 8));
    float4*   boxes_cat = (float4*)  (ws + alloc(BN * 16));
    float*    score     = (float*)   (ws + alloc(BN * 4));
    int*      clsidx    = (int*)     (ws + alloc(BN * 4));
    uint32_t* sv        = (uint32_t*)(ws + alloc(BN * 4));
    float4*   sboxes    = (float4*)  (ws + alloc(BN * 16));
    float*    sscore    = (float*)   (ws + alloc(BN * 4));
    int*      scls      = (int*)     (ws + alloc(BN * 4));
    uint32_t* ssv       = (uint32_t*)(ws + alloc(BN * 4));
    uint32_t* suppg     = (uint32_t*)(ws + alloc((size_t)NBATCH * NW * 4));
    int*      nvalid    = (int*)     (ws + alloc(NBATCH * 4));

    hipMemsetAsync(nvalid, 0, NBATCH * 4, stream);

    int nblk = (int)((BN + 255) / 256);
    prep_kernel<<<nblk, 256, 0, stream>>>(p3b, p3c, p3k, p4b, p4c, p4k, p5b, p5c, p5k,
                                          keys, boxes_cat, score, clsidx, sv);

    dim3 rgrid((NTOT + 255) / 256, NBATCH);
    rank_kernel<<<rgrid, 256, 0, stream>>>(keys, boxes_cat, score, clsidx, sv,
                                           sboxes, sscore, scls, ssv, nvalid);

    size_t smem = (size_t)LDS_CAP * 16 + (size_t)NW * 4 * 2;
    smem = (smem + 15) & ~(size_t)15;
    hipFuncSetAttribute((const void*)nms_kernel, hipFuncAttributeMaxDynamicSharedMemorySize, (int)smem);
    nms_kernel<<<NBATCH, 1024, smem, stream>>>(sboxes, ssv, nvalid, suppg);

    out_kernel<<<nblk, 256, 0, stream>>>(sboxes, sscore, scls, ssv, suppg, out);
}

// Round 2
// 2716.075 us; speedup vs baseline: 2.4156x; 2.4156x over previous
//
#include <hip/hip_runtime.h>
#include <stdint.h>

#define NB3 8112
#define NB4 2028
#define NB5 507
#define NTOT 10647           // 8112 + 2028 + 507
#define NBATCH 4
#define NCLS 20
#define NW32 333             // ceil(10647 / 32)
#define NW64 167             // ceil(10647 / 64)
#define LDS_CAP 9984         // boxes staged in LDS (fallback kernel)
#define CONF_THR_F 0.1f
#define IOU_THR_F 0.45f

typedef unsigned long long u64;

// ---------------------------------------------------------------------------
// Kernel A: per-box score / class argmax / sort key
// ---------------------------------------------------------------------------
__global__ void prep_kernel(const float* __restrict__ p3b, const float* __restrict__ p3c, const float* __restrict__ p3k,
                            const float* __restrict__ p4b, const float* __restrict__ p4c, const float* __restrict__ p4k,
                            const float* __restrict__ p5b, const float* __restrict__ p5c, const float* __restrict__ p5k,
                            uint64_t* __restrict__ keys, float4* __restrict__ boxes_cat,
                            float* __restrict__ score, int* __restrict__ clsidx, uint32_t* __restrict__ svout)
{
#pragma clang fp contract(off)
    int idx = blockIdx.x * 256 + threadIdx.x;
    if (idx >= NBATCH * NTOT) return;
    int b = idx / NTOT;
    int i = idx - b * NTOT;

    const float* bx; const float* cf; const float* cl; int n, off;
    if (i < NB3)            { bx = p3b; cf = p3c; cl = p3k; n = NB3; off = i; }
    else if (i < NB3 + NB4) { bx = p4b; cf = p4c; cl = p4k; n = NB4; off = i - NB3; }
    else                    { bx = p5b; cf = p5c; cl = p5k; n = NB5; off = i - NB3 - NB4; }

    size_t e = (size_t)b * n + off;
    float4 box = *(const float4*)(bx + e * 4);
    float conf = cf[e];
    const float* c = cl + e * NCLS;
    float m = c[0]; int mi = 0;
    #pragma unroll
    for (int k = 1; k < NCLS; ++k) { float v = c[k]; if (v > m) { m = v; mi = k; } }

    bool valid = conf > CONF_THR_F;
    float s = valid ? conf * m : 0.0f;           // exact: single f32 mul, no fma
    uint32_t sb = __float_as_uint(s);            // s >= 0 -> bits monotonic
    keys[idx]      = ((uint64_t)sb << 32) | (uint32_t)(0xFFFFFFFFu - (uint32_t)i);
    boxes_cat[idx] = box;
    score[idx]     = s;
    clsidx[idx]    = mi;
    svout[idx]     = valid ? 1u : 0u;
}

// ---------------------------------------------------------------------------
// Kernel B: stable descending rank sort (rank = #keys strictly greater),
// scatter sorted arrays, build valid bitmap (u64 words) per image
// ---------------------------------------------------------------------------
__global__ void rank_kernel(const uint64_t* __restrict__ keys,
                            const float4* __restrict__ boxes_cat,
                            const float* __restrict__ score,
                            const int* __restrict__ clsidx,
                            const uint32_t* __restrict__ sv,
                            float4* __restrict__ sboxes, float* __restrict__ sscore,
                            int* __restrict__ scls, uint32_t* __restrict__ ssv,
                            u64* __restrict__ validbits, int* __restrict__ nvalid)
{
    int b = blockIdx.y;
    int i = blockIdx.x * 256 + threadIdx.x;
    const uint64_t* kb = keys + (size_t)b * NTOT;
    uint64_t mykey = (i < NTOT) ? kb[i] : 0ull;

    __shared__ uint64_t tile[256];
    int rank = 0;
    for (int t0 = 0; t0 < NTOT; t0 += 256) {
        int j = t0 + threadIdx.x;
        tile[threadIdx.x] = (j < NTOT) ? kb[j] : 0ull;   // 0 never > any real key
        __syncthreads();
        #pragma unroll 8
        for (int t = 0; t < 256; ++t) rank += (tile[t] > mykey) ? 1 : 0;
        __syncthreads();
    }

    if (i < NTOT) {
        size_t src = (size_t)b * NTOT + i;
        size_t dst = (size_t)b * NTOT + rank;
        sboxes[dst] = boxes_cat[src];
        sscore[dst] = score[src];
        scls[dst]   = clsidx[src];
        uint32_t v  = sv[src];
        ssv[dst]    = v;
        if (v) {
            atomicOr(&validbits[(size_t)b * NW64 + (rank >> 6)], 1ull << (rank & 63));
            atomicMax(&nvalid[b], rank + 1);
        }
    }
}

// ---------------------------------------------------------------------------
// Kernel C1 (fast path): build suppression bit-matrix.
// mask[(b*NTOT + i)*NW64 + c] = 64-bit word: bit k set iff IoU(i, c*64+k)>thr
// and (c*64+k) > i. Only upper-triangle chunks (c >= r) are written.
// ---------------------------------------------------------------------------
__global__ void __launch_bounds__(256) mask_build(const float4* __restrict__ sboxes,
                                                  u64* __restrict__ mask)
{
#pragma clang fp contract(off)
    int c = blockIdx.y;
    if (c < blockIdx.x * 4) return;              // whole block below diagonal
    int b = blockIdx.z;
    int sub = threadIdx.x >> 6;
    int lane = threadIdx.x & 63;
    int r = blockIdx.x * 4 + sub;

    __shared__ float4 cb[64];
    __shared__ float  ca[64];
    if (threadIdx.x < 64) {
        int j = c * 64 + threadIdx.x;
        float4 bj = sboxes[(size_t)b * NTOT + (j < NTOT ? j : NTOT - 1)];
        cb[threadIdx.x] = bj;
        ca[threadIdx.x] = (bj.z - bj.x) * (bj.w - bj.y);
    }
    __syncthreads();

    if (r >= NW64 || c < r) return;              // wave below diagonal / OOB
    int i = r * 64 + lane;
    float4 bi = sboxes[(size_t)b * NTOT + (i < NTOT ? i : NTOT - 1)];
    float ax1 = bi.x, ay1 = bi.y, ax2 = bi.z, ay2 = bi.w;
    float area_i = (ax2 - ax1) * (ay2 - ay1);

    u64 m = 0;
    #pragma unroll 8
    for (int k = 0; k < 64; ++k) {
        float4 bj = cb[k];
        float xx1 = fmaxf(bj.x, ax1);
        float yy1 = fmaxf(bj.y, ay1);
        float xx2 = fminf(bj.z, ax2);
        float yy2 = fminf(bj.w, ay2);
        float w = fmaxf(xx2 - xx1, 0.0f);
        float h = fmaxf(yy2 - yy1, 0.0f);
        float inter = w * h;
        float iou = inter / ((area_i + ca[k]) - inter);   // matches ref op order
        bool set = (iou > IOU_THR_F) && (c > r || k > lane) && (c * 64 + k < NTOT);
        m |= (u64)set << k;
    }
    if (i < NTOT) mask[((size_t)b * NTOT + i) * NW64 + c] = m;
}

// ---------------------------------------------------------------------------
// Kernel C2 (fast path): greedy resolve, 1 wave per image, bitmap in regs.
// Lane l holds removed-words {l, 64+l, 128+l}.
// ---------------------------------------------------------------------------
__global__ void __launch_bounds__(64) resolve_kernel(const u64* __restrict__ mask,
                                                     const u64* __restrict__ validbits,
                                                     u64* __restrict__ rem_out)
{
    int b = blockIdx.x;
    int lane = threadIdx.x;
    const u64* M = mask + (size_t)b * NTOT * NW64;
    const u64* V = validbits + (size_t)b * NW64;

    u64 rem0 = 0, rem1 = 0, rem2 = 0;

    for (int g = 0; g < NW64; ++g) {
        int slot = g >> 6;
        u64 rv = (slot == 0) ? rem0 : (slot == 1) ? rem1 : rem2;
        u64 cur = __shfl(rv, g & 63, 64);
        u64 alive = V[g] & ~cur;

        // diag word for row (g*64+lane): intra-group suppression bits
        int drow = g * 64 + lane; if (drow >= NTOT) drow = NTOT - 1;
        u64 dlane = M[(size_t)drow * NW64 + g];

        u64 pending = alive;
        while (pending) {
            int i = __ffsll(pending) - 1;        // next kept box in this group
            u64 d = __shfl(dlane, i, 64);
            pending &= ~(d | (1ull << i));
            // OR row (g*64+i) into register-resident removed bitmap.
            // Only words >= g matter (and only those are guaranteed written).
            size_t row = ((size_t)g * 64 + i) * NW64;
            if (lane >= g)                        rem0 |= M[row + lane];
            if (64 + lane >= g)                   rem1 |= M[row + 64 + lane];
            if (128 + lane >= g && 128 + lane < NW64) rem2 |= M[row + 128 + lane];
        }
    }

    rem_out[(size_t)b * NW64 + lane]      = rem0;
    rem_out[(size_t)b * NW64 + 64 + lane] = rem1;
    if (128 + lane < NW64) rem_out[(size_t)b * NW64 + 128 + lane] = rem2;
}

// ---------------------------------------------------------------------------
// Fallback (small ws): original single-block NMS. Writes u32 words into the
// same u64 rem buffer (little-endian layout makes bit positions identical).
// ---------------------------------------------------------------------------
extern __shared__ unsigned char nms_smem[];

__global__ void __launch_bounds__(1024) nms_kernel(const float4* __restrict__ sboxes,
                                                   const uint32_t* __restrict__ ssv,
                                                   const int* __restrict__ nvalid_arr,
                                                   uint32_t* __restrict__ supp_out)
{
#pragma clang fp contract(off)
    int b = blockIdx.x;
    float4*   lbox = (float4*)nms_smem;
    uint32_t* supp = (uint32_t*)(nms_smem + (size_t)LDS_CAP * 16);
    uint32_t* svb  = supp + NW32;

    int nv = nvalid_arr[b];
    const float4* gb = sboxes + (size_t)b * NTOT;
    const uint32_t* gv = ssv + (size_t)b * NTOT;

    for (int t = threadIdx.x; t < NW32; t += 1024) { supp[t] = 0u; svb[t] = 0u; }
    __syncthreads();
    for (int t = threadIdx.x; t < nv; t += 1024) {
        if (t < LDS_CAP) lbox[t] = gb[t];
        if (gv[t]) atomicOr(&svb[t >> 5], 1u << (t & 31));
    }
    __syncthreads();

    for (int i = 0; i < nv; ++i) {
        uint32_t sw = supp[i >> 5];
        if ((sw >> (i & 31)) & 1u) continue;
        uint32_t vw = svb[i >> 5];
        if (!((vw >> (i & 31)) & 1u)) continue;

        float4 bi = (i < LDS_CAP) ? lbox[i] : gb[i];
        float ax1 = bi.x, ay1 = bi.y, ax2 = bi.z, ay2 = bi.w;
        float area_i = (ax2 - ax1) * (ay2 - ay1);

        for (int j = i + 1 + (int)threadIdx.x; j < nv; j += 1024) {
            float4 bj = (j < LDS_CAP) ? lbox[j] : gb[j];
            float xx1 = fmaxf(bj.x, ax1);
            float yy1 = fmaxf(bj.y, ay1);
            float xx2 = fminf(bj.z, ax2);
            float yy2 = fminf(bj.w, ay2);
            float w = fmaxf(xx2 - xx1, 0.0f);
            float h = fmaxf(yy2 - yy1, 0.0f);
            float inter  = w * h;
            float area_j = (bj.z - bj.x) * (bj.w - bj.y);
            float iou = inter / ((area_i + area_j) - inter);
            if (iou > IOU_THR_F) atomicOr(&supp[j >> 5], 1u << (j & 31));
        }
        __syncthreads();
    }

    __syncthreads();
    // u64 layout: u32 word w of image b lives at u32-index b*(2*NW64) + w
    for (int t = threadIdx.x; t < NW32; t += 1024)
        supp_out[(size_t)b * (2 * NW64) + t] = supp[t];
}

// ---------------------------------------------------------------------------
// Kernel D: assemble outputs: dets [B,N,6] then keep [B,N] (as 0/1 floats)
// ---------------------------------------------------------------------------
__global__ void out_kernel(const float4* __restrict__ sboxes, const float* __restrict__ sscore,
                           const int* __restrict__ scls, const uint32_t* __restrict__ ssv,
                           const u64* __restrict__ rem, float* __restrict__ out)
{
    int idx = blockIdx.x * 256 + threadIdx.x;
    if (idx >= NBATCH * NTOT) return;
    int b = idx / NTOT;
    int p = idx - b * NTOT;

    float4 box = sboxes[idx];
    u64 rw = rem[(size_t)b * NW64 + (p >> 6)];
    bool keep = (ssv[idx] != 0u) && !((rw >> (p & 63)) & 1ull);
    float sc = keep ? sscore[idx] : 0.0f;

    float* d = out + (size_t)idx * 6;
    d[0] = box.x; d[1] = box.y; d[2] = box.z; d[3] = box.w;
    d[4] = sc;    d[5] = (float)scls[idx];
    out[(size_t)NBATCH * NTOT * 6 + idx] = keep ? 1.0f : 0.0f;
}

// ---------------------------------------------------------------------------
extern "C" void kernel_launch(void* const* d_in, const int* in_sizes, int n_in,
                              void* d_out, int out_size, void* d_ws, size_t ws_size,
                              hipStream_t stream)
{
    const float* p3b = (const float*)d_in[0];
    const float* p3c = (const float*)d_in[1];
    const float* p3k = (const float*)d_in[2];
    const float* p4b = (const float*)d_in[3];
    const float* p4c = (const float*)d_in[4];
    const float* p4k = (const float*)d_in[5];
    const float* p5b = (const float*)d_in[6];
    const float* p5c = (const float*)d_in[7];
    const float* p5k = (const float*)d_in[8];
    float* out = (float*)d_out;

    // workspace carve-up (256B aligned slabs)
    char* ws = (char*)d_ws;
    size_t off = 0;
    auto alloc = [&](size_t bytes) { size_t o = off; off += (bytes + 255) & ~(size_t)255; return o; };
    const size_t BN = (size_t)NBATCH * NTOT;
    uint64_t* keys      = (uint64_t*)(ws + alloc(BN * 8));
    float4*   boxes_cat = (float4*)  (ws + alloc(BN * 16));
    float*    score     = (float*)   (ws + alloc(BN * 4));
    int*      clsidx    = (int*)     (ws + alloc(BN * 4));
    uint32_t* sv        = (uint32_t*)(ws + alloc(BN * 4));
    float4*   sboxes    = (float4*)  (ws + alloc(BN * 16));
    float*    sscore    = (float*)   (ws + alloc(BN * 4));
    int*      scls      = (int*)     (ws + alloc(BN * 4));
    uint32_t* ssv       = (uint32_t*)(ws + alloc(BN * 4));
    u64*      rem64     = (u64*)     (ws + alloc((size_t)NBATCH * NW64 * 8));
    u64*      validbits = (u64*)     (ws + alloc((size_t)NBATCH * NW64 * 8));
    int*      nvalid    = (int*)     (ws + alloc(NBATCH * 4));
    u64*      mask      = (u64*)     (ws + alloc((size_t)NBATCH * NTOT * NW64 * 8));
    bool fast = (off <= ws_size);

    hipMemsetAsync(nvalid, 0, NBATCH * 4, stream);
    hipMemsetAsync(validbits, 0, (size_t)NBATCH * NW64 * 8, stream);

    int nblk = (int)((BN + 255) / 256);
    prep_kernel<<<nblk, 256, 0, stream>>>(p3b, p3c, p3k, p4b, p4c, p4k, p5b, p5c, p5k,
                                          keys, boxes_cat, score, clsidx, sv);

    dim3 rgrid((NTOT + 255) / 256, NBATCH);
    rank_kernel<<<rgrid, 256, 0, stream>>>(keys, boxes_cat, score, clsidx, sv,
                                           sboxes, sscore, scls, ssv, validbits, nvalid);

    if (fast) {
        dim3 mgrid((NW64 + 3) / 4, NW64, NBATCH);
        mask_build<<<mgrid, 256, 0, stream>>>(sboxes, mask);
        resolve_kernel<<<NBATCH, 64, 0, stream>>>(mask, validbits, rem64);
    } else {
        hipMemsetAsync(rem64, 0, (size_t)NBATCH * NW64 * 8, stream);
        size_t smem = (size_t)LDS_CAP * 16 + (size_t)NW32 * 4 * 2;
        smem = (smem + 15) & ~(size_t)15;
        hipFuncSetAttribute((const void*)nms_kernel, hipFuncAttributeMaxDynamicSharedMemorySize, (int)smem);
        nms_kernel<<<NBATCH, 1024, smem, stream>>>(sboxes, ssv, nvalid, (uint32_t*)rem64);
    }

    out_kernel<<<nblk, 256, 0, stream>>>(sboxes, sscore, scls, ssv, rem64, out);
}

// Round 3
// 1060.026 us; speedup vs baseline: 6.1894x; 2.5623x over previous
//
#include <hip/hip_runtime.h>
#include <stdint.h>

#define NB3 8112
#define NB4 2028
#define NB5 507
#define NTOT 10647           // 8112 + 2028 + 507
#define NBATCH 4
#define NCLS 20
#define NW32 333             // ceil(10647 / 32)
#define NW64 167             // ceil(10647 / 64)
#define LDS_CAP 9984         // boxes staged in LDS (fallback kernel)
#define CONF_THR_F 0.1f
#define IOU_THR_F 0.45f

typedef unsigned long long u64;

// ---------------------------------------------------------------------------
// Kernel A: per-box score / class argmax / sort key
// ---------------------------------------------------------------------------
__global__ void prep_kernel(const float* __restrict__ p3b, const float* __restrict__ p3c, const float* __restrict__ p3k,
                            const float* __restrict__ p4b, const float* __restrict__ p4c, const float* __restrict__ p4k,
                            const float* __restrict__ p5b, const float* __restrict__ p5c, const float* __restrict__ p5k,
                            uint64_t* __restrict__ keys, float4* __restrict__ boxes_cat,
                            float* __restrict__ score, int* __restrict__ clsidx, uint32_t* __restrict__ svout)
{
#pragma clang fp contract(off)
    int idx = blockIdx.x * 256 + threadIdx.x;
    if (idx >= NBATCH * NTOT) return;
    int b = idx / NTOT;
    int i = idx - b * NTOT;

    const float* bx; const float* cf; const float* cl; int n, off;
    if (i < NB3)            { bx = p3b; cf = p3c; cl = p3k; n = NB3; off = i; }
    else if (i < NB3 + NB4) { bx = p4b; cf = p4c; cl = p4k; n = NB4; off = i - NB3; }
    else                    { bx = p5b; cf = p5c; cl = p5k; n = NB5; off = i - NB3 - NB4; }

    size_t e = (size_t)b * n + off;
    float4 box = *(const float4*)(bx + e * 4);
    float conf = cf[e];
    const float* c = cl + e * NCLS;
    float m = c[0]; int mi = 0;
    #pragma unroll
    for (int k = 1; k < NCLS; ++k) { float v = c[k]; if (v > m) { m = v; mi = k; } }

    bool valid = conf > CONF_THR_F;
    float s = valid ? conf * m : 0.0f;           // exact: single f32 mul, no fma
    uint32_t sb = __float_as_uint(s);            // s >= 0 -> bits monotonic
    keys[idx]      = ((uint64_t)sb << 32) | (uint32_t)(0xFFFFFFFFu - (uint32_t)i);
    boxes_cat[idx] = box;
    score[idx]     = s;
    clsidx[idx]    = mi;
    svout[idx]     = valid ? 1u : 0u;
}

// ---------------------------------------------------------------------------
// Kernel B: stable descending rank sort (rank = #keys strictly greater),
// scatter sorted arrays, build valid bitmap (u64 words) per image
// ---------------------------------------------------------------------------
__global__ void rank_kernel(const uint64_t* __restrict__ keys,
                            const float4* __restrict__ boxes_cat,
                            const float* __restrict__ score,
                            const int* __restrict__ clsidx,
                            const uint32_t* __restrict__ sv,
                            float4* __restrict__ sboxes, float* __restrict__ sscore,
                            int* __restrict__ scls, uint32_t* __restrict__ ssv,
                            u64* __restrict__ validbits, int* __restrict__ nvalid)
{
    int b = blockIdx.y;
    int i = blockIdx.x * 256 + threadIdx.x;
    const uint64_t* kb = keys + (size_t)b * NTOT;
    uint64_t mykey = (i < NTOT) ? kb[i] : 0ull;

    __shared__ uint64_t tile[256];
    int rank = 0;
    for (int t0 = 0; t0 < NTOT; t0 += 256) {
        int j = t0 + threadIdx.x;
        tile[threadIdx.x] = (j < NTOT) ? kb[j] : 0ull;   // 0 never > any real key
        __syncthreads();
        #pragma unroll 8
        for (int t = 0; t < 256; ++t) rank += (tile[t] > mykey) ? 1 : 0;
        __syncthreads();
    }

    if (i < NTOT) {
        size_t src = (size_t)b * NTOT + i;
        size_t dst = (size_t)b * NTOT + rank;
        sboxes[dst] = boxes_cat[src];
        sscore[dst] = score[src];
        scls[dst]   = clsidx[src];
        uint32_t v  = sv[src];
        ssv[dst]    = v;
        if (v) {
            atomicOr(&validbits[(size_t)b * NW64 + (rank >> 6)], 1ull << (rank & 63));
            atomicMax(&nvalid[b], rank + 1);
        }
    }
}

// ---------------------------------------------------------------------------
// Kernel C1 (fast path): build suppression bit-matrix + compact diag blocks.
// mask[(b*NTOT + i)*NW64 + c] = 64-bit word: bit k set iff IoU(i, c*64+k)>thr
// and (c*64+k) > i. Only upper-triangle chunks (c >= r) are written.
// diag[(b*NW64 + g)*64 + lane] = mask word of row g*64+lane at column-chunk g
// (coalesced copy of the diagonal block, for resolve_kernel).
// ---------------------------------------------------------------------------
__global__ void __launch_bounds__(256) mask_build(const float4* __restrict__ sboxes,
                                                  u64* __restrict__ mask,
                                                  u64* __restrict__ diag)
{
#pragma clang fp contract(off)
    int c = blockIdx.y;
    if (c < blockIdx.x * 4) return;              // whole block below diagonal
    int b = blockIdx.z;
    int sub = threadIdx.x >> 6;
    int lane = threadIdx.x & 63;
    int r = blockIdx.x * 4 + sub;

    __shared__ float4 cb[64];
    __shared__ float  ca[64];
    if (threadIdx.x < 64) {
        int j = c * 64 + threadIdx.x;
        float4 bj = sboxes[(size_t)b * NTOT + (j < NTOT ? j : NTOT - 1)];
        cb[threadIdx.x] = bj;
        ca[threadIdx.x] = (bj.z - bj.x) * (bj.w - bj.y);
    }
    __syncthreads();

    if (r >= NW64 || c < r) return;              // wave below diagonal / OOB
    int i = r * 64 + lane;
    float4 bi = sboxes[(size_t)b * NTOT + (i < NTOT ? i : NTOT - 1)];
    float ax1 = bi.x, ay1 = bi.y, ax2 = bi.z, ay2 = bi.w;
    float area_i = (ax2 - ax1) * (ay2 - ay1);

    u64 m = 0;
    #pragma unroll 8
    for (int k = 0; k < 64; ++k) {
        float4 bj = cb[k];
        float xx1 = fmaxf(bj.x, ax1);
        float yy1 = fmaxf(bj.y, ay1);
        float xx2 = fminf(bj.z, ax2);
        float yy2 = fminf(bj.w, ay2);
        float w = fmaxf(xx2 - xx1, 0.0f);
        float h = fmaxf(yy2 - yy1, 0.0f);
        float inter = w * h;
        float iou = inter / ((area_i + ca[k]) - inter);   // matches ref op order
        bool set = (iou > IOU_THR_F) && (c > r || k > lane) && (c * 64 + k < NTOT);
        m |= (u64)set << k;
    }
    if (i < NTOT) {
        mask[((size_t)b * NTOT + i) * NW64 + c] = m;
        if (c == r) diag[((size_t)b * NW64 + r) * 64 + lane] = m;
    }
}

// ---------------------------------------------------------------------------
// Kernel C2 (fast path): greedy resolve, 1 wave per image, bitmap in regs.
// Lane l holds removed-words {l, 64+l, 128+l}. Per group: decide the kept set
// with a pure shfl chain (no loads on the decision path), then OR the kept
// rows in batches of 8 (24 independent loads -> one latency round-trip).
// ---------------------------------------------------------------------------
__global__ void __launch_bounds__(64) resolve_kernel(const u64* __restrict__ mask,
                                                     const u64* __restrict__ diag,
                                                     const u64* __restrict__ validbits,
                                                     u64* __restrict__ rem_out)
{
    int b = blockIdx.x;
    int lane = threadIdx.x;
    const u64* M = mask + (size_t)b * NTOT * NW64;
    const u64* D = diag + (size_t)b * NW64 * 64;
    const u64* V = validbits + (size_t)b * NW64;

    u64 rem0 = 0, rem1 = 0, rem2 = 0;
    int wc = 128 + lane; if (wc >= NW64) wc = NW64 - 1;   // clamped 3rd-word idx

    // preload group 0 state
    u64 Vg = V[0];
    u64 dl = D[lane];

    for (int g = 0; g < NW64; ++g) {
        // prefetch next group's V and diag (clamped; issued before batch waits)
        int gn = (g + 1 < NW64) ? g + 1 : g;
        u64 Vn = V[gn];
        u64 dn = D[(size_t)gn * 64 + lane];

        int slot = g >> 6;
        u64 rv = (slot == 0) ? rem0 : (slot == 1) ? rem1 : rem2;
        u64 cur = __shfl(rv, g & 63, 64);
        u64 alive = Vg & ~cur;

        // intra-group greedy: pure register/shfl chain -> kept mask
        u64 kept = 0, pending = alive;
        while (pending) {
            int i = __ffsll(pending) - 1;
            kept |= 1ull << i;
            u64 d = __shfl(dl, i, 64);
            pending &= ~(d | (1ull << i));
        }

        // lane-predicate masks (words < g were never written; drop them)
        u64 p0m = (lane >= g) ? ~0ull : 0ull;
        u64 p1m = (64 + lane >= g) ? ~0ull : 0ull;
        u64 p2m = ((128 + lane < NW64) && (128 + lane >= g)) ? ~0ull : 0ull;

        // batched row-OR: 8 rows per iteration, 24 independent loads
        u64 km = kept;
        while (km) {
            uint32_t ro[8]; u64 sm[8];
            int ilast = 0;
            #pragma unroll
            for (int s = 0; s < 8; ++s) {
                bool has = (km != 0);
                int i = has ? (__ffsll(km) - 1) : ilast;
                sm[s] = has ? ~0ull : 0ull;
                ro[s] = (uint32_t)(((uint32_t)g * 64u + (uint32_t)i) * (uint32_t)NW64);
                km &= (km - 1);
                ilast = i;
            }
            u64 la[8], lb[8], lc[8];
            #pragma unroll
            for (int s = 0; s < 8; ++s) {
                const u64* R = M + ro[s];
                la[s] = R[lane];
                lb[s] = R[64 + lane];
                lc[s] = R[wc];
            }
            u64 oa = 0, ob = 0, oc = 0;
            #pragma unroll
            for (int s = 0; s < 8; ++s) {
                oa |= la[s] & sm[s];
                ob |= lb[s] & sm[s];
                oc |= lc[s] & sm[s];
            }
            rem0 |= oa & p0m;
            rem1 |= ob & p1m;
            rem2 |= oc & p2m;
        }

        Vg = Vn; dl = dn;
    }

    rem_out[(size_t)b * NW64 + lane]      = rem0;
    rem_out[(size_t)b * NW64 + 64 + lane] = rem1;
    if (128 + lane < NW64) rem_out[(size_t)b * NW64 + 128 + lane] = rem2;
}

// ---------------------------------------------------------------------------
// Fallback (small ws): original single-block NMS. Writes u32 words into the
// same u64 rem buffer (little-endian layout makes bit positions identical).
// ---------------------------------------------------------------------------
extern __shared__ unsigned char nms_smem[];

__global__ void __launch_bounds__(1024) nms_kernel(const float4* __restrict__ sboxes,
                                                   const uint32_t* __restrict__ ssv,
                                                   const int* __restrict__ nvalid_arr,
                                                   uint32_t* __restrict__ supp_out)
{
#pragma clang fp contract(off)
    int b = blockIdx.x;
    float4*   lbox = (float4*)nms_smem;
    uint32_t* supp = (uint32_t*)(nms_smem + (size_t)LDS_CAP * 16);
    uint32_t* svb  = supp + NW32;

    int nv = nvalid_arr[b];
    const float4* gb = sboxes + (size_t)b * NTOT;
    const uint32_t* gv = ssv + (size_t)b * NTOT;

    for (int t = threadIdx.x; t < NW32; t += 1024) { supp[t] = 0u; svb[t] = 0u; }
    __syncthreads();
    for (int t = threadIdx.x; t < nv; t += 1024) {
        if (t < LDS_CAP) lbox[t] = gb[t];
        if (gv[t]) atomicOr(&svb[t >> 5], 1u << (t & 31));
    }
    __syncthreads();

    for (int i = 0; i < nv; ++i) {
        uint32_t sw = supp[i >> 5];
        if ((sw >> (i & 31)) & 1u) continue;
        uint32_t vw = svb[i >> 5];
        if (!((vw >> (i & 31)) & 1u)) continue;

        float4 bi = (i < LDS_CAP) ? lbox[i] : gb[i];
        float ax1 = bi.x, ay1 = bi.y, ax2 = bi.z, ay2 = bi.w;
        float area_i = (ax2 - ax1) * (ay2 - ay1);

        for (int j = i + 1 + (int)threadIdx.x; j < nv; j += 1024) {
            float4 bj = (j < LDS_CAP) ? lbox[j] : gb[j];
            float xx1 = fmaxf(bj.x, ax1);
            float yy1 = fmaxf(bj.y, ay1);
            float xx2 = fminf(bj.z, ax2);
            float yy2 = fminf(bj.w, ay2);
            float w = fmaxf(xx2 - xx1, 0.0f);
            float h = fmaxf(yy2 - yy1, 0.0f);
            float inter  = w * h;
            float area_j = (bj.z - bj.x) * (bj.w - bj.y);
            float iou = inter / ((area_i + area_j) - inter);
            if (iou > IOU_THR_F) atomicOr(&supp[j >> 5], 1u << (j & 31));
        }
        __syncthreads();
    }

    __syncthreads();
    // u64 layout: u32 word w of image b lives at u32-index b*(2*NW64) + w
    for (int t = threadIdx.x; t < NW32; t += 1024)
        supp_out[(size_t)b * (2 * NW64) + t] = supp[t];
}

// ---------------------------------------------------------------------------
// Kernel D: assemble outputs: dets [B,N,6] then keep [B,N] (as 0/1 floats)
// ---------------------------------------------------------------------------
__global__ void out_kernel(const float4* __restrict__ sboxes, const float* __restrict__ sscore,
                           const int* __restrict__ scls, const uint32_t* __restrict__ ssv,
                           const u64* __restrict__ rem, float* __restrict__ out)
{
    int idx = blockIdx.x * 256 + threadIdx.x;
    if (idx >= NBATCH * NTOT) return;
    int b = idx / NTOT;
    int p = idx - b * NTOT;

    float4 box = sboxes[idx];
    u64 rw = rem[(size_t)b * NW64 + (p >> 6)];
    bool keep = (ssv[idx] != 0u) && !((rw >> (p & 63)) & 1ull);
    float sc = keep ? sscore[idx] : 0.0f;

    float* d = out + (size_t)idx * 6;
    d[0] = box.x; d[1] = box.y; d[2] = box.z; d[3] = box.w;
    d[4] = sc;    d[5] = (float)scls[idx];
    out[(size_t)NBATCH * NTOT * 6 + idx] = keep ? 1.0f : 0.0f;
}

// ---------------------------------------------------------------------------
extern "C" void kernel_launch(void* const* d_in, const int* in_sizes, int n_in,
                              void* d_out, int out_size, void* d_ws, size_t ws_size,
                              hipStream_t stream)
{
    const float* p3b = (const float*)d_in[0];
    const float* p3c = (const float*)d_in[1];
    const float* p3k = (const float*)d_in[2];
    const float* p4b = (const float*)d_in[3];
    const float* p4c = (const float*)d_in[4];
    const float* p4k = (const float*)d_in[5];
    const float* p5b = (const float*)d_in[6];
    const float* p5c = (const float*)d_in[7];
    const float* p5k = (const float*)d_in[8];
    float* out = (float*)d_out;

    // workspace carve-up (256B aligned slabs)
    char* ws = (char*)d_ws;
    size_t off = 0;
    auto alloc = [&](size_t bytes) { size_t o = off; off += (bytes + 255) & ~(size_t)255; return o; };
    const size_t BN = (size_t)NBATCH * NTOT;
    uint64_t* keys      = (uint64_t*)(ws + alloc(BN * 8));
    float4*   boxes_cat = (float4*)  (ws + alloc(BN * 16));
    float*    score     = (float*)   (ws + alloc(BN * 4));
    int*      clsidx    = (int*)     (ws + alloc(BN * 4));
    uint32_t* sv        = (uint32_t*)(ws + alloc(BN * 4));
    float4*   sboxes    = (float4*)  (ws + alloc(BN * 16));
    float*    sscore    = (float*)   (ws + alloc(BN * 4));
    int*      scls      = (int*)     (ws + alloc(BN * 4));
    uint32_t* ssv       = (uint32_t*)(ws + alloc(BN * 4));
    u64*      rem64     = (u64*)     (ws + alloc((size_t)NBATCH * NW64 * 8));
    u64*      validbits = (u64*)     (ws + alloc((size_t)NBATCH * NW64 * 8));
    int*      nvalid    = (int*)     (ws + alloc(NBATCH * 4));
    u64*      diag      = (u64*)     (ws + alloc((size_t)NBATCH * NW64 * 64 * 8));
    u64*      mask      = (u64*)     (ws + alloc((size_t)NBATCH * NTOT * NW64 * 8));
    bool fast = (off <= ws_size);

    hipMemsetAsync(nvalid, 0, NBATCH * 4, stream);
    hipMemsetAsync(validbits, 0, (size_t)NBATCH * NW64 * 8, stream);

    int nblk = (int)((BN + 255) / 256);
    prep_kernel<<<nblk, 256, 0, stream>>>(p3b, p3c, p3k, p4b, p4c, p4k, p5b, p5c, p5k,
                                          keys, boxes_cat, score, clsidx, sv);

    dim3 rgrid((NTOT + 255) / 256, NBATCH);
    rank_kernel<<<rgrid, 256, 0, stream>>>(keys, boxes_cat, score, clsidx, sv,
                                           sboxes, sscore, scls, ssv, validbits, nvalid);

    if (fast) {
        dim3 mgrid((NW64 + 3) / 4, NW64, NBATCH);
        mask_build<<<mgrid, 256, 0, stream>>>(sboxes, mask, diag);
        resolve_kernel<<<NBATCH, 64, 0, stream>>>(mask, diag, validbits, rem64);
    } else {
        hipMemsetAsync(rem64, 0, (size_t)NBATCH * NW64 * 8, stream);
        size_t smem = (size_t)LDS_CAP * 16 + (size_t)NW32 * 4 * 2;
        smem = (smem + 15) & ~(size_t)15;
        hipFuncSetAttribute((const void*)nms_kernel, hipFuncAttributeMaxDynamicSharedMemorySize, (int)smem);
        nms_kernel<<<NBATCH, 1024, smem, stream>>>(sboxes, ssv, nvalid, (uint32_t*)rem64);
    }

    out_kernel<<<nblk, 256, 0, stream>>>(sboxes, sscore, scls, ssv, rem64, out);
}